// Round 9
// baseline (248.891 us; speedup 1.0000x reference)
//
#include <hip/hip_runtime.h>

// GCN 2-layer, R9: CSR-build parallelism fix (R8 postmortem: bin at 1.9% occ,
// 196 blocks, LDS-atomic serialization ~ duration).
//   bin: 1024 edges/block (782 blocks); bucket = 128 dsts (391 buckets).
//   Xs = bf16(dinv ⊙ X)                        (fused into bucket_csr)
//   A1 = bf16(dinv[r]*(Xs[r] + Σ Xs[c]))       (gather1, in d_out)
//   Ts = bf16( (dinv⊙relu(A1@W1+b1)) @ W2 )    (gemm_fused, H1 via LDS)
//   out = relu(dinv[r]*(Ts[r] + Σ Ts[c]) + b2) (gather2, fused epilogue)
// No per-item global atomic queues (R7 lesson). edge_index is int32.

typedef short bf16x8 __attribute__((ext_vector_type(8)));
typedef float f32x4 __attribute__((ext_vector_type(4)));

#define LDSTRIDE 264   // 16 rows * 264 bf16 = 528 B/row: b128-aligned
#define BSHIFT 7       // 128 dsts per bucket
#define BMASK 127

__device__ inline unsigned short f2bf(float f) {          // RNE
    unsigned int u = __float_as_uint(f);
    u += 0x7FFF + ((u >> 16) & 1);
    return (unsigned short)(u >> 16);
}
__device__ inline float bf2f(unsigned short h) {
    return __uint_as_float(((unsigned int)h) << 16);
}

// ---------- W swizzle into MFMA b-frag order (device helper) ----------
__device__ inline void swz1(const float* W, unsigned short* Ws, int K, int N, int i) {
    int k = i / N, n = i % N;
    int KC = K >> 5;
    size_t d = ((((size_t)(n >> 4) * KC + (k >> 5)) * 64) + ((k >> 3) & 3) * 16 + (n & 15)) * 8
               + (k & 7);
    Ws[d] = f2bf(W[i]);
}

// ---------- pass 1: bin edges by dst>>7 (4 B packed) + wswz tail block ----------
// 1024 edges/block for occupancy (R8: 4096/block -> 1.9% occ, serialized).
__global__ __launch_bounds__(256) void bin_kernel(
    const int* __restrict__ src, const int* __restrict__ dst,
    int* __restrict__ bcur, unsigned int* __restrict__ bbuf,
    const float* __restrict__ W1, const float* __restrict__ W2,
    unsigned short* __restrict__ W1s, unsigned short* __restrict__ W2s,
    int E, int cap, int nbuck) {
    int t = threadIdx.x;
    if (blockIdx.x == gridDim.x - 1) {       // fused weight swizzle block
        for (int i = t; i < 32768; i += 256) swz1(W1, W1s, 128, 256, i);
        for (int i = t; i < 32768; i += 256) swz1(W2, W2s, 256, 128, i);
        return;
    }
    __shared__ int cnt[512];
    __shared__ int base[512];
    for (int i = t; i < nbuck; i += 256) cnt[i] = 0;
    __syncthreads();
    int e0 = blockIdx.x * 1024;
    unsigned int p_[4];
    int b_[4];
#pragma unroll
    for (int i = 0; i < 4; i++) {
        int e = e0 + i * 256 + t;
        if (e < E) {
            int s = src[e], d = dst[e];
            b_[i] = d >> BSHIFT;
            p_[i] = ((unsigned)(d & BMASK) << 24) | (unsigned)s;   // N < 2^24
            atomicAdd(&cnt[b_[i]], 1);
        } else b_[i] = -1;
    }
    __syncthreads();
    for (int b = t; b < nbuck; b += 256) {
        int c = cnt[b];
        base[b] = (c > 0) ? atomicAdd(&bcur[b], c) : 0;
    }
    __syncthreads();
    for (int i = t; i < nbuck; i += 256) cnt[i] = 0;   // reuse as cursor
    __syncthreads();
#pragma unroll
    for (int i = 0; i < 4; i++) {
        if (b_[i] >= 0) {
            int b = b_[i];
            int p = base[b] + atomicAdd(&cnt[b], 1);
            if (p < cap) bbuf[(size_t)b * cap + p] = p_[i];
        }
    }
}

// ---------- pass 2: per-bucket (128 dsts) CSR + dinv + fused Xs ----------
__global__ __launch_bounds__(256) void bucket_csr_kernel(
    const int* __restrict__ bcur, const unsigned int* __restrict__ bbuf,
    const float* __restrict__ x,
    int* __restrict__ col, int* __restrict__ rowbeg, int* __restrict__ rowend,
    float* __restrict__ dinv, unsigned short* __restrict__ Xs, int N, int cap) {
    __shared__ int ldeg[128];
    __shared__ int lrp[256];
    __shared__ float sdv[128];
    int b = blockIdx.x, t = threadIdx.x;
    int cnt = min(bcur[b], cap);
    if (t < 128) ldeg[t] = 0;
    __syncthreads();
    const unsigned int* mybuf = bbuf + (size_t)b * cap;
    for (int i = t; i < cnt; i += 256)
        atomicAdd(&ldeg[mybuf[i] >> 24], 1);
    __syncthreads();
    int v = (t < 128) ? ldeg[t] : 0;
    lrp[t] = v;
    __syncthreads();
    for (int off = 1; off < 128; off <<= 1) {    // inclusive scan (128 live)
        int u = (t >= off) ? lrp[t - off] : 0;
        __syncthreads();
        lrp[t] += u;
        __syncthreads();
    }
    int excl = lrp[t] - v;
    int gbase = b * cap;
    if (t < 128) {
        int r = b * 128 + t;
        float dv = rsqrtf((float)v + 1.0f);      // self-loop adds 1
        sdv[t] = dv;
        if (r < N) {
            rowbeg[r] = gbase + excl;
            rowend[r] = gbase + excl + v;
            dinv[r] = dv;
        }
        ldeg[t] = excl;    // reuse as cursor
    }
    __syncthreads();
    for (int i = t; i < cnt; i += 256) {
        unsigned int pr = mybuf[i];
        int p = atomicAdd(&ldeg[pr >> 24], 1);
        col[gbase + p] = (int)(pr & 0xffffffu);
    }
    // fused Xs: rows b*128..+127, coalesced ushort4
    int rbase = b * 128;
    for (int i = t; i < 128 * 32; i += 256) {
        int rl = i >> 5;
        int gr = rbase + rl;
        if (gr >= N) break;
        float s = sdv[rl];
        float4 xv = ((const float4*)x)[(size_t)gr * 32 + (i & 31)];
        ushort4 o;
        o.x = f2bf(xv.x * s); o.y = f2bf(xv.y * s);
        o.z = f2bf(xv.z * s); o.w = f2bf(xv.w * s);
        ((ushort4*)Xs)[(size_t)gr * 32 + (i & 31)] = o;
    }
}

// ---------- gather: half-wave per row, ushort4/lane, unroll x4 ----------
// OB!=null: OB[r] = bf16(dinv[r]*acc)   (gather1)
// else:     OF[r] = relu(dinv[r]*acc + bias)   (gather2)
__global__ __launch_bounds__(256) void gather_kernel(
    const int* __restrict__ rowbeg, const int* __restrict__ rowend,
    const int* __restrict__ col, const unsigned short* __restrict__ P,
    const float* __restrict__ dinv, const float* __restrict__ bias,
    unsigned short* __restrict__ OB, float* __restrict__ OF, int N) {
    int gid = blockIdx.x * blockDim.x + threadIdx.x;
    int r = gid >> 5;
    if (r >= N) return;
    int lane = gid & 31;
    const size_t off = (size_t)lane * 4;
    const unsigned short* Pf = P + off;

    ushort4 u = *(const ushort4*)(Pf + (size_t)r * 128);
    float ax = bf2f(u.x), ay = bf2f(u.y), az = bf2f(u.z), aw = bf2f(u.w);

    int beg = rowbeg[r], end = rowend[r];
    int i = beg;
    for (; i + 3 < end; i += 4) {
        int c0 = col[i], c1 = col[i + 1], c2 = col[i + 2], c3 = col[i + 3];
        ushort4 a = *(const ushort4*)(Pf + (size_t)c0 * 128);
        ushort4 b = *(const ushort4*)(Pf + (size_t)c1 * 128);
        ushort4 c = *(const ushort4*)(Pf + (size_t)c2 * 128);
        ushort4 d = *(const ushort4*)(Pf + (size_t)c3 * 128);
        ax += bf2f(a.x) + bf2f(b.x) + bf2f(c.x) + bf2f(d.x);
        ay += bf2f(a.y) + bf2f(b.y) + bf2f(c.y) + bf2f(d.y);
        az += bf2f(a.z) + bf2f(b.z) + bf2f(c.z) + bf2f(d.z);
        aw += bf2f(a.w) + bf2f(b.w) + bf2f(c.w) + bf2f(d.w);
    }
    for (; i < end; i++) {
        ushort4 a = *(const ushort4*)(Pf + (size_t)col[i] * 128);
        ax += bf2f(a.x); ay += bf2f(a.y); az += bf2f(a.z); aw += bf2f(a.w);
    }
    float s = dinv[r];
    if (OB) {
        ushort4 o;
        o.x = f2bf(ax * s); o.y = f2bf(ay * s);
        o.z = f2bf(az * s); o.w = f2bf(aw * s);
        *(ushort4*)(OB + (size_t)r * 128 + off) = o;
    } else {
        float4 bb = *(const float4*)(bias + off);
        float4 o;
        o.x = fmaxf(ax * s + bb.x, 0.f);
        o.y = fmaxf(ay * s + bb.y, 0.f);
        o.z = fmaxf(az * s + bb.z, 0.f);
        o.w = fmaxf(aw * s + bb.w, 0.f);
        *(float4*)(OF + (size_t)r * 128 + off) = o;
    }
}

// ---------- fused GEMM: Ts = bf16( (dinv⊙relu(A1@W1+b1)) @ W2 ) ----------
__global__ __launch_bounds__(256) void gemm_fused_kernel(
    const unsigned short* __restrict__ A, const unsigned short* __restrict__ W1s,
    const unsigned short* __restrict__ W2s, const float* __restrict__ bias,
    const float* __restrict__ dinv, unsigned short* __restrict__ T, int M) {
    __shared__ unsigned short lh[4][16 * LDSTRIDE];   // 4 waves x 8448 B
    int wave = threadIdx.x >> 6;
    int lane = threadIdx.x & 63;
    int mt = blockIdx.x * 4 + wave;
    int m0 = mt * 16;
    bool active = (m0 < M);
    int mrow = lane & 15, quad = lane >> 4;
    unsigned short* myl = lh[wave];

    if (active) {
        bf16x8 a[4];
        const unsigned short* arow = A + (size_t)(m0 + mrow) * 128 + quad * 8;
#pragma unroll
        for (int kc = 0; kc < 4; kc++) a[kc] = *(const bf16x8*)(arow + kc * 32);
        float dv[4];
#pragma unroll
        for (int i = 0; i < 4; i++) {
            int gr = m0 + quad * 4 + i;
            dv[i] = dinv[gr < M ? gr : M - 1];
        }
        const bf16x8* w1v = (const bf16x8*)W1s;
        for (int nt = 0; nt < 16; nt++) {
            f32x4 acc = {0.f, 0.f, 0.f, 0.f};
#pragma unroll
            for (int kc = 0; kc < 4; kc++) {
                bf16x8 b = w1v[(nt * 4 + kc) * 64 + lane];
                acc = __builtin_amdgcn_mfma_f32_16x16x32_bf16(a[kc], b, acc, 0, 0, 0);
            }
            int colc = nt * 16 + mrow;
            float bb = bias[colc];
#pragma unroll
            for (int i = 0; i < 4; i++) {
                float v = fmaxf(acc[i] + bb, 0.f) * dv[i];
                myl[(quad * 4 + i) * LDSTRIDE + colc] = f2bf(v);
            }
        }
    }
    __syncthreads();
    if (active) {
        bf16x8 h[8];
        const unsigned short* hrow = myl + mrow * LDSTRIDE + quad * 8;
#pragma unroll
        for (int kc = 0; kc < 8; kc++) h[kc] = *(const bf16x8*)(hrow + kc * 32);
        const bf16x8* w2v = (const bf16x8*)W2s;
        for (int nt = 0; nt < 8; nt++) {
            f32x4 acc = {0.f, 0.f, 0.f, 0.f};
#pragma unroll
            for (int kc = 0; kc < 8; kc++) {
                bf16x8 b = w2v[(nt * 8 + kc) * 64 + lane];
                acc = __builtin_amdgcn_mfma_f32_16x16x32_bf16(h[kc], b, acc, 0, 0, 0);
            }
            int colc = nt * 16 + mrow;
#pragma unroll
            for (int i = 0; i < 4; i++) {
                int gr = m0 + quad * 4 + i;
                if (gr < M) T[(size_t)gr * 128 + colc] = f2bf(acc[i]);
            }
        }
    }
}

extern "C" void kernel_launch(void* const* d_in, const int* in_sizes, int n_in,
                              void* d_out, int out_size, void* d_ws, size_t ws_size,
                              hipStream_t stream) {
    const float* x  = (const float*)d_in[0];
    const int* ei   = (const int*)d_in[1];     // int32 (JAX x64 disabled)
    const float* W1 = (const float*)d_in[2];
    const float* b1 = (const float*)d_in[3];
    const float* W2 = (const float*)d_in[4];
    const float* b2 = (const float*)d_in[5];
    float* out      = (float*)d_out;

    const int N = in_sizes[0] / 128;
    const int E = in_sizes[1] / 2;
    const int* src = ei;
    const int* dst = ei + E;

    const int nbuck = (N + BMASK) >> BSHIFT;                // 391
    const int cap = E / nbuck + E / (4 * nbuck) + 512;      // ~3069

    // Workspace: dinv | Ts | Xs | W1s | W2s | rowbeg | rowend | ctrl | bbuf | col
    float* ws = (float*)d_ws;
    size_t Np = ((size_t)N + 255) & ~(size_t)255;
    float*          dinv = ws;
    unsigned short* Ts   = (unsigned short*)(dinv + Np);    // N*128 bf16
    unsigned short* Xs   = Ts + (size_t)N * 128;            // N*128 bf16
    unsigned short* W1s  = Xs + (size_t)N * 128;            // 32768
    unsigned short* W2s  = W1s + 32768;                     // 32768
    int* rowbeg = (int*)(W2s + 32768);                      // N
    int* rowend = rowbeg + Np;                              // N
    int* ctrl   = rowend + Np;                              // bcur[512]
    int* bcur   = ctrl;
    unsigned int* bbuf = (unsigned int*)(ctrl + 512);       // nbuck*cap packed
    int* col    = (int*)(bbuf + (size_t)nbuck * cap);       // nbuck*cap
    unsigned short* A1 = (unsigned short*)d_out;            // N*128 bf16 scratch

    // 1. bucketed CSR build (+wswz tail block) + dinv + Xs
    hipMemsetAsync(ctrl, 0, 512 * sizeof(int), stream);
    int nbins = (E + 1023) / 1024;                          // 782
    bin_kernel<<<nbins + 1, 256, 0, stream>>>(src, dst, bcur, bbuf,
                                              W1, W2, W1s, W2s, E, cap, nbuck);
    bucket_csr_kernel<<<nbuck, 256, 0, stream>>>(bcur, bbuf, x, col, rowbeg, rowend,
                                                 dinv, Xs, N, cap);

    // 2. gather1 -> A1 bf16 in d_out
    int gth = N * 32;
    gather_kernel<<<(gth + 255) / 256, 256, 0, stream>>>(rowbeg, rowend, col, Xs,
                                                         dinv, nullptr, A1, nullptr, N);

    // 3. fused GEMM1+GEMM2 -> Ts
    int mtiles = (N + 15) / 16;
    gemm_fused_kernel<<<(mtiles + 3) / 4, 256, 0, stream>>>(A1, W1s, W2s, b1, dinv, Ts, N);

    // 4. gather2 + fused bias/relu -> out
    gather_kernel<<<(gth + 255) / 256, 256, 0, stream>>>(rowbeg, rowend, col, Ts,
                                                         dinv, b2, nullptr, out, N);
}

// Round 10
// 212.184 us; speedup vs baseline: 1.1730x; 1.1730x over previous
//
#include <hip/hip_runtime.h>

// GCN 2-layer, R10: un-fuse the wswz straggler (R9 postmortem: bin's duration
// was its slowest block = the serial 65k-element swizzle tail, not the edge
// payload). bin: 2048 edges/block, 391 blocks, 128-dst buckets. Gather
// unroll x8.
//   Xs = bf16(dinv ⊙ X)                        (fused into bucket_csr)
//   A1 = bf16(dinv[r]*(Xs[r] + Σ Xs[c]))       (gather1, in d_out)
//   Ts = bf16( (dinv⊙relu(A1@W1+b1)) @ W2 )    (gemm_fused, H1 via LDS)
//   out = relu(dinv[r]*(Ts[r] + Σ Ts[c]) + b2) (gather2, fused epilogue)
// No per-item global atomic queues (R7 lesson). edge_index is int32.

typedef short bf16x8 __attribute__((ext_vector_type(8)));
typedef float f32x4 __attribute__((ext_vector_type(4)));

#define LDSTRIDE 264   // 16 rows * 264 bf16 = 528 B/row: b128-aligned
#define BSHIFT 7       // 128 dsts per bucket
#define BMASK 127

__device__ inline unsigned short f2bf(float f) {          // RNE
    unsigned int u = __float_as_uint(f);
    u += 0x7FFF + ((u >> 16) & 1);
    return (unsigned short)(u >> 16);
}
__device__ inline float bf2f(unsigned short h) {
    return __uint_as_float(((unsigned int)h) << 16);
}

// ---------- W swizzle into MFMA b-frag order (own kernel, 1 elem/thread) ----------
__device__ inline void swz1(const float* W, unsigned short* Ws, int K, int N, int i) {
    int k = i / N, n = i % N;
    int KC = K >> 5;
    size_t d = ((((size_t)(n >> 4) * KC + (k >> 5)) * 64) + ((k >> 3) & 3) * 16 + (n & 15)) * 8
               + (k & 7);
    Ws[d] = f2bf(W[i]);
}
__global__ void wswz_kernel(const float* __restrict__ W1, const float* __restrict__ W2,
                            unsigned short* __restrict__ W1s, unsigned short* __restrict__ W2s) {
    int i = blockIdx.x * blockDim.x + threadIdx.x;
    if (i < 32768) swz1(W1, W1s, 128, 256, i);
    else if (i < 65536) swz1(W2, W2s, 256, 128, i - 32768);
}

// ---------- pass 1: bin edges by dst>>7 (4 B packed) ----------
__global__ __launch_bounds__(256) void bin_kernel(
    const int* __restrict__ src, const int* __restrict__ dst,
    int* __restrict__ bcur, unsigned int* __restrict__ bbuf,
    int E, int cap, int nbuck) {
    __shared__ int cnt[512];
    __shared__ int base[512];
    int t = threadIdx.x;
    for (int i = t; i < nbuck; i += 256) cnt[i] = 0;
    __syncthreads();
    int e0 = blockIdx.x * 2048;
    unsigned int p_[8];
    int b_[8];
#pragma unroll
    for (int i = 0; i < 8; i++) {
        int e = e0 + i * 256 + t;
        if (e < E) {
            int s = src[e], d = dst[e];
            b_[i] = d >> BSHIFT;
            p_[i] = ((unsigned)(d & BMASK) << 24) | (unsigned)s;   // N < 2^24
            atomicAdd(&cnt[b_[i]], 1);
        } else b_[i] = -1;
    }
    __syncthreads();
    for (int b = t; b < nbuck; b += 256) {
        int c = cnt[b];
        base[b] = (c > 0) ? atomicAdd(&bcur[b], c) : 0;
    }
    __syncthreads();
    for (int i = t; i < nbuck; i += 256) cnt[i] = 0;   // reuse as cursor
    __syncthreads();
#pragma unroll
    for (int i = 0; i < 8; i++) {
        if (b_[i] >= 0) {
            int b = b_[i];
            int p = base[b] + atomicAdd(&cnt[b], 1);
            if (p < cap) bbuf[(size_t)b * cap + p] = p_[i];
        }
    }
}

// ---------- pass 2: per-bucket (128 dsts) CSR + dinv + fused Xs ----------
__global__ __launch_bounds__(256) void bucket_csr_kernel(
    const int* __restrict__ bcur, const unsigned int* __restrict__ bbuf,
    const float* __restrict__ x,
    int* __restrict__ col, int* __restrict__ rowbeg, int* __restrict__ rowend,
    float* __restrict__ dinv, unsigned short* __restrict__ Xs, int N, int cap) {
    __shared__ int ldeg[128];
    __shared__ int lrp[256];
    __shared__ float sdv[128];
    int b = blockIdx.x, t = threadIdx.x;
    int cnt = min(bcur[b], cap);
    if (t < 128) ldeg[t] = 0;
    __syncthreads();
    const unsigned int* mybuf = bbuf + (size_t)b * cap;
    for (int i = t; i < cnt; i += 256)
        atomicAdd(&ldeg[mybuf[i] >> 24], 1);
    __syncthreads();
    int v = (t < 128) ? ldeg[t] : 0;
    lrp[t] = v;
    __syncthreads();
    for (int off = 1; off < 128; off <<= 1) {    // inclusive scan (128 live)
        int u = (t >= off) ? lrp[t - off] : 0;
        __syncthreads();
        lrp[t] += u;
        __syncthreads();
    }
    int excl = lrp[t] - v;
    int gbase = b * cap;
    if (t < 128) {
        int r = b * 128 + t;
        float dv = rsqrtf((float)v + 1.0f);      // self-loop adds 1
        sdv[t] = dv;
        if (r < N) {
            rowbeg[r] = gbase + excl;
            rowend[r] = gbase + excl + v;
            dinv[r] = dv;
        }
        ldeg[t] = excl;    // reuse as cursor
    }
    __syncthreads();
    for (int i = t; i < cnt; i += 256) {
        unsigned int pr = mybuf[i];
        int p = atomicAdd(&ldeg[pr >> 24], 1);
        col[gbase + p] = (int)(pr & 0xffffffu);
    }
    // fused Xs: rows b*128..+127, coalesced ushort4
    int rbase = b * 128;
    for (int i = t; i < 128 * 32; i += 256) {
        int rl = i >> 5;
        int gr = rbase + rl;
        if (gr >= N) break;
        float s = sdv[rl];
        float4 xv = ((const float4*)x)[(size_t)gr * 32 + (i & 31)];
        ushort4 o;
        o.x = f2bf(xv.x * s); o.y = f2bf(xv.y * s);
        o.z = f2bf(xv.z * s); o.w = f2bf(xv.w * s);
        ((ushort4*)Xs)[(size_t)gr * 32 + (i & 31)] = o;
    }
}

// ---------- gather: half-wave per row, ushort4/lane, unroll x8 ----------
// OB!=null: OB[r] = bf16(dinv[r]*acc)   (gather1)
// else:     OF[r] = relu(dinv[r]*acc + bias)   (gather2)
__global__ __launch_bounds__(256) void gather_kernel(
    const int* __restrict__ rowbeg, const int* __restrict__ rowend,
    const int* __restrict__ col, const unsigned short* __restrict__ P,
    const float* __restrict__ dinv, const float* __restrict__ bias,
    unsigned short* __restrict__ OB, float* __restrict__ OF, int N) {
    int gid = blockIdx.x * blockDim.x + threadIdx.x;
    int r = gid >> 5;
    if (r >= N) return;
    int lane = gid & 31;
    const size_t off = (size_t)lane * 4;
    const unsigned short* Pf = P + off;

    ushort4 u = *(const ushort4*)(Pf + (size_t)r * 128);
    float ax = bf2f(u.x), ay = bf2f(u.y), az = bf2f(u.z), aw = bf2f(u.w);

    int beg = rowbeg[r], end = rowend[r];
    int i = beg;
    for (; i + 7 < end; i += 8) {
        ushort4 v0 = *(const ushort4*)(Pf + (size_t)col[i + 0] * 128);
        ushort4 v1 = *(const ushort4*)(Pf + (size_t)col[i + 1] * 128);
        ushort4 v2 = *(const ushort4*)(Pf + (size_t)col[i + 2] * 128);
        ushort4 v3 = *(const ushort4*)(Pf + (size_t)col[i + 3] * 128);
        ushort4 v4 = *(const ushort4*)(Pf + (size_t)col[i + 4] * 128);
        ushort4 v5 = *(const ushort4*)(Pf + (size_t)col[i + 5] * 128);
        ushort4 v6 = *(const ushort4*)(Pf + (size_t)col[i + 6] * 128);
        ushort4 v7 = *(const ushort4*)(Pf + (size_t)col[i + 7] * 128);
        ax += bf2f(v0.x) + bf2f(v1.x) + bf2f(v2.x) + bf2f(v3.x)
            + bf2f(v4.x) + bf2f(v5.x) + bf2f(v6.x) + bf2f(v7.x);
        ay += bf2f(v0.y) + bf2f(v1.y) + bf2f(v2.y) + bf2f(v3.y)
            + bf2f(v4.y) + bf2f(v5.y) + bf2f(v6.y) + bf2f(v7.y);
        az += bf2f(v0.z) + bf2f(v1.z) + bf2f(v2.z) + bf2f(v3.z)
            + bf2f(v4.z) + bf2f(v5.z) + bf2f(v6.z) + bf2f(v7.z);
        aw += bf2f(v0.w) + bf2f(v1.w) + bf2f(v2.w) + bf2f(v3.w)
            + bf2f(v4.w) + bf2f(v5.w) + bf2f(v6.w) + bf2f(v7.w);
    }
    for (; i < end; i++) {
        ushort4 a = *(const ushort4*)(Pf + (size_t)col[i] * 128);
        ax += bf2f(a.x); ay += bf2f(a.y); az += bf2f(a.z); aw += bf2f(a.w);
    }
    float s = dinv[r];
    if (OB) {
        ushort4 o;
        o.x = f2bf(ax * s); o.y = f2bf(ay * s);
        o.z = f2bf(az * s); o.w = f2bf(aw * s);
        *(ushort4*)(OB + (size_t)r * 128 + off) = o;
    } else {
        float4 bb = *(const float4*)(bias + off);
        float4 o;
        o.x = fmaxf(ax * s + bb.x, 0.f);
        o.y = fmaxf(ay * s + bb.y, 0.f);
        o.z = fmaxf(az * s + bb.z, 0.f);
        o.w = fmaxf(aw * s + bb.w, 0.f);
        *(float4*)(OF + (size_t)r * 128 + off) = o;
    }
}

// ---------- fused GEMM: Ts = bf16( (dinv⊙relu(A1@W1+b1)) @ W2 ) ----------
__global__ __launch_bounds__(256) void gemm_fused_kernel(
    const unsigned short* __restrict__ A, const unsigned short* __restrict__ W1s,
    const unsigned short* __restrict__ W2s, const float* __restrict__ bias,
    const float* __restrict__ dinv, unsigned short* __restrict__ T, int M) {
    __shared__ unsigned short lh[4][16 * LDSTRIDE];   // 4 waves x 8448 B
    int wave = threadIdx.x >> 6;
    int lane = threadIdx.x & 63;
    int mt = blockIdx.x * 4 + wave;
    int m0 = mt * 16;
    bool active = (m0 < M);
    int mrow = lane & 15, quad = lane >> 4;
    unsigned short* myl = lh[wave];

    if (active) {
        bf16x8 a[4];
        const unsigned short* arow = A + (size_t)(m0 + mrow) * 128 + quad * 8;
#pragma unroll
        for (int kc = 0; kc < 4; kc++) a[kc] = *(const bf16x8*)(arow + kc * 32);
        float dv[4];
#pragma unroll
        for (int i = 0; i < 4; i++) {
            int gr = m0 + quad * 4 + i;
            dv[i] = dinv[gr < M ? gr : M - 1];
        }
        const bf16x8* w1v = (const bf16x8*)W1s;
        for (int nt = 0; nt < 16; nt++) {
            f32x4 acc = {0.f, 0.f, 0.f, 0.f};
#pragma unroll
            for (int kc = 0; kc < 4; kc++) {
                bf16x8 b = w1v[(nt * 4 + kc) * 64 + lane];
                acc = __builtin_amdgcn_mfma_f32_16x16x32_bf16(a[kc], b, acc, 0, 0, 0);
            }
            int colc = nt * 16 + mrow;
            float bb = bias[colc];
#pragma unroll
            for (int i = 0; i < 4; i++) {
                float v = fmaxf(acc[i] + bb, 0.f) * dv[i];
                myl[(quad * 4 + i) * LDSTRIDE + colc] = f2bf(v);
            }
        }
    }
    __syncthreads();
    if (active) {
        bf16x8 h[8];
        const unsigned short* hrow = myl + mrow * LDSTRIDE + quad * 8;
#pragma unroll
        for (int kc = 0; kc < 8; kc++) h[kc] = *(const bf16x8*)(hrow + kc * 32);
        const bf16x8* w2v = (const bf16x8*)W2s;
        for (int nt = 0; nt < 8; nt++) {
            f32x4 acc = {0.f, 0.f, 0.f, 0.f};
#pragma unroll
            for (int kc = 0; kc < 8; kc++) {
                bf16x8 b = w2v[(nt * 8 + kc) * 64 + lane];
                acc = __builtin_amdgcn_mfma_f32_16x16x32_bf16(h[kc], b, acc, 0, 0, 0);
            }
            int colc = nt * 16 + mrow;
#pragma unroll
            for (int i = 0; i < 4; i++) {
                int gr = m0 + quad * 4 + i;
                if (gr < M) T[(size_t)gr * 128 + colc] = f2bf(acc[i]);
            }
        }
    }
}

extern "C" void kernel_launch(void* const* d_in, const int* in_sizes, int n_in,
                              void* d_out, int out_size, void* d_ws, size_t ws_size,
                              hipStream_t stream) {
    const float* x  = (const float*)d_in[0];
    const int* ei   = (const int*)d_in[1];     // int32 (JAX x64 disabled)
    const float* W1 = (const float*)d_in[2];
    const float* b1 = (const float*)d_in[3];
    const float* W2 = (const float*)d_in[4];
    const float* b2 = (const float*)d_in[5];
    float* out      = (float*)d_out;

    const int N = in_sizes[0] / 128;
    const int E = in_sizes[1] / 2;
    const int* src = ei;
    const int* dst = ei + E;

    const int nbuck = (N + BMASK) >> BSHIFT;                // 391
    const int cap = E / nbuck + E / (4 * nbuck) + 512;      // ~3069

    // Workspace: dinv | Ts | Xs | W1s | W2s | rowbeg | rowend | ctrl | bbuf | col
    float* ws = (float*)d_ws;
    size_t Np = ((size_t)N + 255) & ~(size_t)255;
    float*          dinv = ws;
    unsigned short* Ts   = (unsigned short*)(dinv + Np);    // N*128 bf16
    unsigned short* Xs   = Ts + (size_t)N * 128;            // N*128 bf16
    unsigned short* W1s  = Xs + (size_t)N * 128;            // 32768
    unsigned short* W2s  = W1s + 32768;                     // 32768
    int* rowbeg = (int*)(W2s + 32768);                      // N
    int* rowend = rowbeg + Np;                              // N
    int* ctrl   = rowend + Np;                              // bcur[512]
    int* bcur   = ctrl;
    unsigned int* bbuf = (unsigned int*)(ctrl + 512);       // nbuck*cap packed
    int* col    = (int*)(bbuf + (size_t)nbuck * cap);       // nbuck*cap
    unsigned short* A1 = (unsigned short*)d_out;            // N*128 bf16 scratch

    // 1. weight swizzle (own kernel — R9's straggler lesson) + CSR build
    hipMemsetAsync(ctrl, 0, 512 * sizeof(int), stream);
    wswz_kernel<<<256, 256, 0, stream>>>(W1, W2, W1s, W2s);
    int nbins = (E + 2047) / 2048;                          // 391
    bin_kernel<<<nbins, 256, 0, stream>>>(src, dst, bcur, bbuf, E, cap, nbuck);
    bucket_csr_kernel<<<nbuck, 256, 0, stream>>>(bcur, bbuf, x, col, rowbeg, rowend,
                                                 dinv, Xs, N, cap);

    // 2. gather1 -> A1 bf16 in d_out
    int gth = N * 32;
    gather_kernel<<<(gth + 255) / 256, 256, 0, stream>>>(rowbeg, rowend, col, Xs,
                                                         dinv, nullptr, A1, nullptr, N);

    // 3. fused GEMM1+GEMM2 -> Ts
    int mtiles = (N + 15) / 16;
    gemm_fused_kernel<<<(mtiles + 3) / 4, 256, 0, stream>>>(A1, W1s, W2s, b1, dinv, Ts, N);

    // 4. gather2 + fused bias/relu -> out
    gather_kernel<<<(gth + 255) / 256, 256, 0, stream>>>(rowbeg, rowend, col, Ts,
                                                         dinv, b2, nullptr, out, N);
}

// Round 12
// 207.458 us; speedup vs baseline: 1.1997x; 1.0228x over previous
//
#include <hip/hip_runtime.h>

// GCN 2-layer, R12 = R11 + ctrl-zero fix (R11 crash: only 256 of 512 ctrl
// ints zeroed -> negative bucket base -> OOB bbuf write).
//   wswz(+ctrl zero) | bin | bucket_csr(dinv,Xs) | gemm_fused | gather2
//   Xs = bf16(dinv ⊙ X)
//   gemm_fused: register-direct gather1 -> MFMA GEMM1 -> LDS -> MFMA GEMM2
//   out = relu(dinv[r]*(Ts[r] + Σ Ts[c]) + b2)   (gather2, fused epilogue)
// Lessons: no global atomic work queues (R7); no serial straggler blocks in
// wide dispatches (R9); zero ALL control memory (R11). edge_index is int32.

typedef short bf16x8 __attribute__((ext_vector_type(8)));
typedef float f32x4 __attribute__((ext_vector_type(4)));

#define LDSTRIDE 264   // 16 rows * 264 bf16 = 528 B/row: b128-aligned
#define BSHIFT 7       // 128 dsts per bucket
#define BMASK 127

__device__ inline unsigned short f2bf(float f) {          // RNE
    unsigned int u = __float_as_uint(f);
    u += 0x7FFF + ((u >> 16) & 1);
    return (unsigned short)(u >> 16);
}
__device__ inline float bf2f(unsigned short h) {
    return __uint_as_float(((unsigned int)h) << 16);
}

// ---------- W swizzle into MFMA b-frag order + ctrl zero ----------
__device__ inline void swz1(const float* W, unsigned short* Ws, int K, int N, int i) {
    int k = i / N, n = i % N;
    int KC = K >> 5;
    size_t d = ((((size_t)(n >> 4) * KC + (k >> 5)) * 64) + ((k >> 3) & 3) * 16 + (n & 15)) * 8
               + (k & 7);
    Ws[d] = f2bf(W[i]);
}
__global__ void wswz_kernel(const float* __restrict__ W1, const float* __restrict__ W2,
                            unsigned short* __restrict__ W1s, unsigned short* __restrict__ W2s,
                            int* __restrict__ ctrl) {
    int i = blockIdx.x * blockDim.x + threadIdx.x;
    if (blockIdx.x == 0) {                     // zero ALL 512 ctrl ints (R11 bug)
        for (int j = threadIdx.x; j < 512; j += 256) ctrl[j] = 0;
    }
    if (i < 32768) swz1(W1, W1s, 128, 256, i);
    else if (i < 65536) swz1(W2, W2s, 256, 128, i - 32768);
}

// ---------- pass 1: bin edges by dst>>7 (4 B packed) ----------
__global__ __launch_bounds__(256) void bin_kernel(
    const int* __restrict__ src, const int* __restrict__ dst,
    int* __restrict__ bcur, unsigned int* __restrict__ bbuf,
    int E, int cap, int nbuck) {
    __shared__ int cnt[512];
    __shared__ int base[512];
    int t = threadIdx.x;
    for (int i = t; i < nbuck; i += 256) cnt[i] = 0;
    __syncthreads();
    int e0 = blockIdx.x * 2048;
    unsigned int p_[8];
    int b_[8];
#pragma unroll
    for (int i = 0; i < 8; i++) {
        int e = e0 + i * 256 + t;
        if (e < E) {
            int s = src[e], d = dst[e];
            b_[i] = d >> BSHIFT;
            p_[i] = ((unsigned)(d & BMASK) << 24) | (unsigned)s;   // N < 2^24
            atomicAdd(&cnt[b_[i]], 1);
        } else b_[i] = -1;
    }
    __syncthreads();
    for (int b = t; b < nbuck; b += 256) {
        int c = cnt[b];
        base[b] = (c > 0) ? atomicAdd(&bcur[b], c) : 0;
    }
    __syncthreads();
    for (int i = t; i < nbuck; i += 256) cnt[i] = 0;   // reuse as cursor
    __syncthreads();
#pragma unroll
    for (int i = 0; i < 8; i++) {
        if (b_[i] >= 0) {
            int b = b_[i];
            int p = base[b] + atomicAdd(&cnt[b], 1);
            if (p >= 0 && p < cap) bbuf[(size_t)b * cap + p] = p_[i];
        }
    }
}

// ---------- pass 2: per-bucket (128 dsts) CSR + dinv + fused Xs ----------
__global__ __launch_bounds__(256) void bucket_csr_kernel(
    const int* __restrict__ bcur, const unsigned int* __restrict__ bbuf,
    const float* __restrict__ x,
    int* __restrict__ col, int* __restrict__ rowbeg, int* __restrict__ rowend,
    float* __restrict__ dinv, unsigned short* __restrict__ Xs, int N, int cap) {
    __shared__ int ldeg[128];
    __shared__ int lrp[256];
    __shared__ float sdv[128];
    int b = blockIdx.x, t = threadIdx.x;
    int cnt = min(max(bcur[b], 0), cap);
    if (t < 128) ldeg[t] = 0;
    __syncthreads();
    const unsigned int* mybuf = bbuf + (size_t)b * cap;
    for (int i = t; i < cnt; i += 256)
        atomicAdd(&ldeg[mybuf[i] >> 24], 1);
    __syncthreads();
    int v = (t < 128) ? ldeg[t] : 0;
    lrp[t] = v;
    __syncthreads();
    for (int off = 1; off < 128; off <<= 1) {    // inclusive scan (128 live)
        int u = (t >= off) ? lrp[t - off] : 0;
        __syncthreads();
        lrp[t] += u;
        __syncthreads();
    }
    int excl = lrp[t] - v;
    int gbase = b * cap;
    if (t < 128) {
        int r = b * 128 + t;
        float dv = rsqrtf((float)v + 1.0f);      // self-loop adds 1
        sdv[t] = dv;
        if (r < N) {
            rowbeg[r] = gbase + excl;
            rowend[r] = gbase + excl + v;
            dinv[r] = dv;
        }
        ldeg[t] = excl;    // reuse as cursor
    }
    __syncthreads();
    for (int i = t; i < cnt; i += 256) {
        unsigned int pr = mybuf[i];
        int p = atomicAdd(&ldeg[pr >> 24], 1);
        col[gbase + p] = (int)(pr & 0xffffffu);
    }
    // fused Xs: rows b*128..+127, coalesced ushort4
    int rbase = b * 128;
    for (int i = t; i < 128 * 32; i += 256) {
        int rl = i >> 5;
        int gr = rbase + rl;
        if (gr >= N) break;
        float s = sdv[rl];
        float4 xv = ((const float4*)x)[(size_t)gr * 32 + (i & 31)];
        ushort4 o;
        o.x = f2bf(xv.x * s); o.y = f2bf(xv.y * s);
        o.z = f2bf(xv.z * s); o.w = f2bf(xv.w * s);
        ((ushort4*)Xs)[(size_t)gr * 32 + (i & 31)] = o;
    }
}

// ---------- gather2: half-wave per row, ushort4/lane, unroll x8, fused epi ----------
__global__ __launch_bounds__(256) void gather2_kernel(
    const int* __restrict__ rowbeg, const int* __restrict__ rowend,
    const int* __restrict__ col, const unsigned short* __restrict__ P,
    const float* __restrict__ dinv, const float* __restrict__ bias,
    float* __restrict__ OF, int N) {
    int gid = blockIdx.x * blockDim.x + threadIdx.x;
    int r = gid >> 5;
    if (r >= N) return;
    int lane = gid & 31;
    const size_t off = (size_t)lane * 4;
    const unsigned short* Pf = P + off;

    ushort4 u = *(const ushort4*)(Pf + (size_t)r * 128);
    float ax = bf2f(u.x), ay = bf2f(u.y), az = bf2f(u.z), aw = bf2f(u.w);

    int beg = rowbeg[r], end = rowend[r];
    int i = beg;
    for (; i + 7 < end; i += 8) {
        ushort4 v0 = *(const ushort4*)(Pf + (size_t)col[i + 0] * 128);
        ushort4 v1 = *(const ushort4*)(Pf + (size_t)col[i + 1] * 128);
        ushort4 v2 = *(const ushort4*)(Pf + (size_t)col[i + 2] * 128);
        ushort4 v3 = *(const ushort4*)(Pf + (size_t)col[i + 3] * 128);
        ushort4 v4 = *(const ushort4*)(Pf + (size_t)col[i + 4] * 128);
        ushort4 v5 = *(const ushort4*)(Pf + (size_t)col[i + 5] * 128);
        ushort4 v6 = *(const ushort4*)(Pf + (size_t)col[i + 6] * 128);
        ushort4 v7 = *(const ushort4*)(Pf + (size_t)col[i + 7] * 128);
        ax += bf2f(v0.x) + bf2f(v1.x) + bf2f(v2.x) + bf2f(v3.x)
            + bf2f(v4.x) + bf2f(v5.x) + bf2f(v6.x) + bf2f(v7.x);
        ay += bf2f(v0.y) + bf2f(v1.y) + bf2f(v2.y) + bf2f(v3.y)
            + bf2f(v4.y) + bf2f(v5.y) + bf2f(v6.y) + bf2f(v7.y);
        az += bf2f(v0.z) + bf2f(v1.z) + bf2f(v2.z) + bf2f(v3.z)
            + bf2f(v4.z) + bf2f(v5.z) + bf2f(v6.z) + bf2f(v7.z);
        aw += bf2f(v0.w) + bf2f(v1.w) + bf2f(v2.w) + bf2f(v3.w)
            + bf2f(v4.w) + bf2f(v5.w) + bf2f(v6.w) + bf2f(v7.w);
    }
    for (; i < end; i++) {
        ushort4 a = *(const ushort4*)(Pf + (size_t)col[i] * 128);
        ax += bf2f(a.x); ay += bf2f(a.y); az += bf2f(a.z); aw += bf2f(a.w);
    }
    float s = dinv[r];
    float4 bb = *(const float4*)(bias + off);
    float4 o;
    o.x = fmaxf(ax * s + bb.x, 0.f);
    o.y = fmaxf(ay * s + bb.y, 0.f);
    o.z = fmaxf(az * s + bb.z, 0.f);
    o.w = fmaxf(aw * s + bb.w, 0.f);
    *(float4*)(OF + (size_t)r * 128 + off) = o;
}

// ---------- fused gather1 + GEMM1 + GEMM2 ----------
// Ts = bf16( (dinv⊙relu( agg(Xs) @W1 + b1 )) @ W2 ),  agg in registers.
// Lane (m=lane&15, quad=lane>>4) owns row m0+m, features kc*32+quad*8..+8.
__global__ __launch_bounds__(256) void gemm_fused_kernel(
    const int* __restrict__ rowbeg, const int* __restrict__ rowend,
    const int* __restrict__ col, const unsigned short* __restrict__ Xs,
    const unsigned short* __restrict__ W1s, const unsigned short* __restrict__ W2s,
    const float* __restrict__ bias, const float* __restrict__ dinv,
    unsigned short* __restrict__ T, int M) {
    __shared__ unsigned short lh[4][16 * LDSTRIDE];   // 4 waves x 8448 B
    int wave = threadIdx.x >> 6;
    int lane = threadIdx.x & 63;
    int mt = blockIdx.x * 4 + wave;
    int m0 = mt * 16;
    bool active = (m0 < M);
    int mrow = lane & 15, quad = lane >> 4;
    unsigned short* myl = lh[wave];

    if (active) {
        int rr = m0 + mrow; if (rr >= M) rr = M - 1;
        // ---- register-direct gather: acc[kc][j] over this row's in-edges ----
        float acc[4][8];
        const unsigned short* base = Xs + quad * 8;
#pragma unroll
        for (int kc = 0; kc < 4; kc++) {
            bf16x8 v = *(const bf16x8*)(base + (size_t)rr * 128 + kc * 32);
#pragma unroll
            for (int j = 0; j < 8; j++) acc[kc][j] = bf2f((unsigned short)v[j]);
        }
        int beg = rowbeg[rr], end = rowend[rr];
        int i = beg;
        for (; i + 1 < end; i += 2) {      // 2 edges x 4 chunks = 8 loads in flight
            size_t c0 = (size_t)col[i] * 128, c1 = (size_t)col[i + 1] * 128;
            bf16x8 p0 = *(const bf16x8*)(base + c0);
            bf16x8 p1 = *(const bf16x8*)(base + c0 + 32);
            bf16x8 p2 = *(const bf16x8*)(base + c0 + 64);
            bf16x8 p3 = *(const bf16x8*)(base + c0 + 96);
            bf16x8 q0 = *(const bf16x8*)(base + c1);
            bf16x8 q1 = *(const bf16x8*)(base + c1 + 32);
            bf16x8 q2 = *(const bf16x8*)(base + c1 + 64);
            bf16x8 q3 = *(const bf16x8*)(base + c1 + 96);
#pragma unroll
            for (int j = 0; j < 8; j++) {
                acc[0][j] += bf2f((unsigned short)p0[j]) + bf2f((unsigned short)q0[j]);
                acc[1][j] += bf2f((unsigned short)p1[j]) + bf2f((unsigned short)q1[j]);
                acc[2][j] += bf2f((unsigned short)p2[j]) + bf2f((unsigned short)q2[j]);
                acc[3][j] += bf2f((unsigned short)p3[j]) + bf2f((unsigned short)q3[j]);
            }
        }
        if (i < end) {
            size_t c0 = (size_t)col[i] * 128;
#pragma unroll
            for (int kc = 0; kc < 4; kc++) {
                bf16x8 p = *(const bf16x8*)(base + c0 + kc * 32);
#pragma unroll
                for (int j = 0; j < 8; j++) acc[kc][j] += bf2f((unsigned short)p[j]);
            }
        }
        float dvr = dinv[rr];
        bf16x8 a[4];
#pragma unroll
        for (int kc = 0; kc < 4; kc++)
#pragma unroll
            for (int j = 0; j < 8; j++)
                a[kc][j] = (short)f2bf(acc[kc][j] * dvr);

        // ---- GEMM1: H1 tile -> LDS (C-layout -> A-layout round trip) ----
        float dv[4];
#pragma unroll
        for (int i2 = 0; i2 < 4; i2++) {
            int gr = m0 + quad * 4 + i2;
            dv[i2] = dinv[gr < M ? gr : M - 1];
        }
        const bf16x8* w1v = (const bf16x8*)W1s;
        for (int nt = 0; nt < 16; nt++) {
            f32x4 c = {0.f, 0.f, 0.f, 0.f};
#pragma unroll
            for (int kc = 0; kc < 4; kc++) {
                bf16x8 b = w1v[(nt * 4 + kc) * 64 + lane];
                c = __builtin_amdgcn_mfma_f32_16x16x32_bf16(a[kc], b, c, 0, 0, 0);
            }
            int colc = nt * 16 + mrow;
            float bb = bias[colc];
#pragma unroll
            for (int i2 = 0; i2 < 4; i2++) {
                float v = fmaxf(c[i2] + bb, 0.f) * dv[i2];
                myl[(quad * 4 + i2) * LDSTRIDE + colc] = f2bf(v);
            }
        }
    }
    __syncthreads();
    if (active) {
        bf16x8 h[8];
        const unsigned short* hrow = myl + mrow * LDSTRIDE + quad * 8;
#pragma unroll
        for (int kc = 0; kc < 8; kc++) h[kc] = *(const bf16x8*)(hrow + kc * 32);
        const bf16x8* w2v = (const bf16x8*)W2s;
        for (int nt = 0; nt < 8; nt++) {
            f32x4 c = {0.f, 0.f, 0.f, 0.f};
#pragma unroll
            for (int kc = 0; kc < 8; kc++) {
                bf16x8 b = w2v[(nt * 8 + kc) * 64 + lane];
                c = __builtin_amdgcn_mfma_f32_16x16x32_bf16(h[kc], b, c, 0, 0, 0);
            }
            int colc = nt * 16 + mrow;
#pragma unroll
            for (int i2 = 0; i2 < 4; i2++) {
                int gr = m0 + quad * 4 + i2;
                if (gr < M) T[(size_t)gr * 128 + colc] = f2bf(c[i2]);
            }
        }
    }
}

extern "C" void kernel_launch(void* const* d_in, const int* in_sizes, int n_in,
                              void* d_out, int out_size, void* d_ws, size_t ws_size,
                              hipStream_t stream) {
    const float* x  = (const float*)d_in[0];
    const int* ei   = (const int*)d_in[1];     // int32 (JAX x64 disabled)
    const float* W1 = (const float*)d_in[2];
    const float* b1 = (const float*)d_in[3];
    const float* W2 = (const float*)d_in[4];
    const float* b2 = (const float*)d_in[5];
    float* out      = (float*)d_out;

    const int N = in_sizes[0] / 128;
    const int E = in_sizes[1] / 2;
    const int* src = ei;
    const int* dst = ei + E;

    const int nbuck = (N + BMASK) >> BSHIFT;                // 391
    const int cap = E / nbuck + E / (4 * nbuck) + 512;      // ~3069

    // Workspace: dinv | Ts | Xs | W1s | W2s | rowbeg | rowend | ctrl | bbuf | col
    float* ws = (float*)d_ws;
    size_t Np = ((size_t)N + 255) & ~(size_t)255;
    float*          dinv = ws;
    unsigned short* Ts   = (unsigned short*)(dinv + Np);    // N*128 bf16
    unsigned short* Xs   = Ts + (size_t)N * 128;            // N*128 bf16
    unsigned short* W1s  = Xs + (size_t)N * 128;            // 32768
    unsigned short* W2s  = W1s + 32768;                     // 32768
    int* rowbeg = (int*)(W2s + 32768);                      // N
    int* rowend = rowbeg + Np;                              // N
    int* ctrl   = rowend + Np;                              // bcur[512]
    int* bcur   = ctrl;
    unsigned int* bbuf = (unsigned int*)(ctrl + 512);       // nbuck*cap packed
    int* col    = (int*)(bbuf + (size_t)nbuck * cap);       // nbuck*cap

    // 1. weight swizzle + ctrl zero, then CSR build
    wswz_kernel<<<256, 256, 0, stream>>>(W1, W2, W1s, W2s, ctrl);
    int nbins = (E + 2047) / 2048;                          // 391
    bin_kernel<<<nbins, 256, 0, stream>>>(src, dst, bcur, bbuf, E, cap, nbuck);
    bucket_csr_kernel<<<nbuck, 256, 0, stream>>>(bcur, bbuf, x, col, rowbeg, rowend,
                                                 dinv, Xs, N, cap);

    // 2. fused gather1 + GEMM1 + GEMM2 -> Ts
    int mtiles = (N + 15) / 16;
    gemm_fused_kernel<<<(mtiles + 3) / 4, 256, 0, stream>>>(rowbeg, rowend, col, Xs,
                                                            W1s, W2s, b1, dinv, Ts, N);

    // 3. gather2 + fused bias/relu -> out
    int gth = N * 32;
    gather2_kernel<<<(gth + 255) / 256, 256, 0, stream>>>(rowbeg, rowend, col, Ts,
                                                          dinv, b2, out, N);
}

// Round 13
// 207.268 us; speedup vs baseline: 1.2008x; 1.0009x over previous
//
#include <hip/hip_runtime.h>

// GCN 2-layer, R13 = R12 + fused-gather MLP x2 (4-edge unroll, 16 loads in
// flight/lane; launch_bounds(256,4) pins 128-VGPR budget matching the 4
// blocks/CU LDS cap).
//   wswz(+ctrl zero) | bin | bucket_csr(dinv,Xs) | gemm_fused | gather2
// Lessons: no global atomic work queues (R7); no serial straggler blocks in
// wide dispatches (R9); zero ALL control memory (R11). edge_index is int32.

typedef short bf16x8 __attribute__((ext_vector_type(8)));
typedef float f32x4 __attribute__((ext_vector_type(4)));

#define LDSTRIDE 264   // 16 rows * 264 bf16 = 528 B/row: b128-aligned
#define BSHIFT 7       // 128 dsts per bucket
#define BMASK 127

__device__ inline unsigned short f2bf(float f) {          // RNE
    unsigned int u = __float_as_uint(f);
    u += 0x7FFF + ((u >> 16) & 1);
    return (unsigned short)(u >> 16);
}
__device__ inline float bf2f(unsigned short h) {
    return __uint_as_float(((unsigned int)h) << 16);
}

// ---------- W swizzle into MFMA b-frag order + ctrl zero ----------
__device__ inline void swz1(const float* W, unsigned short* Ws, int K, int N, int i) {
    int k = i / N, n = i % N;
    int KC = K >> 5;
    size_t d = ((((size_t)(n >> 4) * KC + (k >> 5)) * 64) + ((k >> 3) & 3) * 16 + (n & 15)) * 8
               + (k & 7);
    Ws[d] = f2bf(W[i]);
}
__global__ void wswz_kernel(const float* __restrict__ W1, const float* __restrict__ W2,
                            unsigned short* __restrict__ W1s, unsigned short* __restrict__ W2s,
                            int* __restrict__ ctrl) {
    int i = blockIdx.x * blockDim.x + threadIdx.x;
    if (blockIdx.x == 0) {                     // zero ALL 512 ctrl ints
        for (int j = threadIdx.x; j < 512; j += 256) ctrl[j] = 0;
    }
    if (i < 32768) swz1(W1, W1s, 128, 256, i);
    else if (i < 65536) swz1(W2, W2s, 256, 128, i - 32768);
}

// ---------- pass 1: bin edges by dst>>7 (4 B packed) ----------
__global__ __launch_bounds__(256) void bin_kernel(
    const int* __restrict__ src, const int* __restrict__ dst,
    int* __restrict__ bcur, unsigned int* __restrict__ bbuf,
    int E, int cap, int nbuck) {
    __shared__ int cnt[512];
    __shared__ int base[512];
    int t = threadIdx.x;
    for (int i = t; i < nbuck; i += 256) cnt[i] = 0;
    __syncthreads();
    int e0 = blockIdx.x * 2048;
    unsigned int p_[8];
    int b_[8];
#pragma unroll
    for (int i = 0; i < 8; i++) {
        int e = e0 + i * 256 + t;
        if (e < E) {
            int s = src[e], d = dst[e];
            b_[i] = d >> BSHIFT;
            p_[i] = ((unsigned)(d & BMASK) << 24) | (unsigned)s;   // N < 2^24
            atomicAdd(&cnt[b_[i]], 1);
        } else b_[i] = -1;
    }
    __syncthreads();
    for (int b = t; b < nbuck; b += 256) {
        int c = cnt[b];
        base[b] = (c > 0) ? atomicAdd(&bcur[b], c) : 0;
    }
    __syncthreads();
    for (int i = t; i < nbuck; i += 256) cnt[i] = 0;   // reuse as cursor
    __syncthreads();
#pragma unroll
    for (int i = 0; i < 8; i++) {
        if (b_[i] >= 0) {
            int b = b_[i];
            int p = base[b] + atomicAdd(&cnt[b], 1);
            if (p >= 0 && p < cap) bbuf[(size_t)b * cap + p] = p_[i];
        }
    }
}

// ---------- pass 2: per-bucket (128 dsts) CSR + dinv + fused Xs ----------
__global__ __launch_bounds__(256) void bucket_csr_kernel(
    const int* __restrict__ bcur, const unsigned int* __restrict__ bbuf,
    const float* __restrict__ x,
    int* __restrict__ col, int* __restrict__ rowbeg, int* __restrict__ rowend,
    float* __restrict__ dinv, unsigned short* __restrict__ Xs, int N, int cap) {
    __shared__ int ldeg[128];
    __shared__ int lrp[256];
    __shared__ float sdv[128];
    int b = blockIdx.x, t = threadIdx.x;
    int cnt = min(max(bcur[b], 0), cap);
    if (t < 128) ldeg[t] = 0;
    __syncthreads();
    const unsigned int* mybuf = bbuf + (size_t)b * cap;
    for (int i = t; i < cnt; i += 256)
        atomicAdd(&ldeg[mybuf[i] >> 24], 1);
    __syncthreads();
    int v = (t < 128) ? ldeg[t] : 0;
    lrp[t] = v;
    __syncthreads();
    for (int off = 1; off < 128; off <<= 1) {    // inclusive scan (128 live)
        int u = (t >= off) ? lrp[t - off] : 0;
        __syncthreads();
        lrp[t] += u;
        __syncthreads();
    }
    int excl = lrp[t] - v;
    int gbase = b * cap;
    if (t < 128) {
        int r = b * 128 + t;
        float dv = rsqrtf((float)v + 1.0f);      // self-loop adds 1
        sdv[t] = dv;
        if (r < N) {
            rowbeg[r] = gbase + excl;
            rowend[r] = gbase + excl + v;
            dinv[r] = dv;
        }
        ldeg[t] = excl;    // reuse as cursor
    }
    __syncthreads();
    for (int i = t; i < cnt; i += 256) {
        unsigned int pr = mybuf[i];
        int p = atomicAdd(&ldeg[pr >> 24], 1);
        col[gbase + p] = (int)(pr & 0xffffffu);
    }
    // fused Xs: rows b*128..+127, coalesced ushort4
    int rbase = b * 128;
    for (int i = t; i < 128 * 32; i += 256) {
        int rl = i >> 5;
        int gr = rbase + rl;
        if (gr >= N) break;
        float s = sdv[rl];
        float4 xv = ((const float4*)x)[(size_t)gr * 32 + (i & 31)];
        ushort4 o;
        o.x = f2bf(xv.x * s); o.y = f2bf(xv.y * s);
        o.z = f2bf(xv.z * s); o.w = f2bf(xv.w * s);
        ((ushort4*)Xs)[(size_t)gr * 32 + (i & 31)] = o;
    }
}

// ---------- gather2: half-wave per row, ushort4/lane, unroll x8, fused epi ----------
__global__ __launch_bounds__(256) void gather2_kernel(
    const int* __restrict__ rowbeg, const int* __restrict__ rowend,
    const int* __restrict__ col, const unsigned short* __restrict__ P,
    const float* __restrict__ dinv, const float* __restrict__ bias,
    float* __restrict__ OF, int N) {
    int gid = blockIdx.x * blockDim.x + threadIdx.x;
    int r = gid >> 5;
    if (r >= N) return;
    int lane = gid & 31;
    const size_t off = (size_t)lane * 4;
    const unsigned short* Pf = P + off;

    ushort4 u = *(const ushort4*)(Pf + (size_t)r * 128);
    float ax = bf2f(u.x), ay = bf2f(u.y), az = bf2f(u.z), aw = bf2f(u.w);

    int beg = rowbeg[r], end = rowend[r];
    int i = beg;
    for (; i + 7 < end; i += 8) {
        ushort4 v0 = *(const ushort4*)(Pf + (size_t)col[i + 0] * 128);
        ushort4 v1 = *(const ushort4*)(Pf + (size_t)col[i + 1] * 128);
        ushort4 v2 = *(const ushort4*)(Pf + (size_t)col[i + 2] * 128);
        ushort4 v3 = *(const ushort4*)(Pf + (size_t)col[i + 3] * 128);
        ushort4 v4 = *(const ushort4*)(Pf + (size_t)col[i + 4] * 128);
        ushort4 v5 = *(const ushort4*)(Pf + (size_t)col[i + 5] * 128);
        ushort4 v6 = *(const ushort4*)(Pf + (size_t)col[i + 6] * 128);
        ushort4 v7 = *(const ushort4*)(Pf + (size_t)col[i + 7] * 128);
        ax += bf2f(v0.x) + bf2f(v1.x) + bf2f(v2.x) + bf2f(v3.x)
            + bf2f(v4.x) + bf2f(v5.x) + bf2f(v6.x) + bf2f(v7.x);
        ay += bf2f(v0.y) + bf2f(v1.y) + bf2f(v2.y) + bf2f(v3.y)
            + bf2f(v4.y) + bf2f(v5.y) + bf2f(v6.y) + bf2f(v7.y);
        az += bf2f(v0.z) + bf2f(v1.z) + bf2f(v2.z) + bf2f(v3.z)
            + bf2f(v4.z) + bf2f(v5.z) + bf2f(v6.z) + bf2f(v7.z);
        aw += bf2f(v0.w) + bf2f(v1.w) + bf2f(v2.w) + bf2f(v3.w)
            + bf2f(v4.w) + bf2f(v5.w) + bf2f(v6.w) + bf2f(v7.w);
    }
    for (; i < end; i++) {
        ushort4 a = *(const ushort4*)(Pf + (size_t)col[i] * 128);
        ax += bf2f(a.x); ay += bf2f(a.y); az += bf2f(a.z); aw += bf2f(a.w);
    }
    float s = dinv[r];
    float4 bb = *(const float4*)(bias + off);
    float4 o;
    o.x = fmaxf(ax * s + bb.x, 0.f);
    o.y = fmaxf(ay * s + bb.y, 0.f);
    o.z = fmaxf(az * s + bb.z, 0.f);
    o.w = fmaxf(aw * s + bb.w, 0.f);
    *(float4*)(OF + (size_t)r * 128 + off) = o;
}

// ---------- fused gather1 + GEMM1 + GEMM2 ----------
// Ts = bf16( (dinv⊙relu( agg(Xs) @W1 + b1 )) @ W2 ),  agg in registers.
// Lane (m=lane&15, quad=lane>>4) owns row m0+m, features kc*32+quad*8..+8.
// 4-edge unroll: 16 loads in flight per lane (R12 was 8 -> latency-bound).
__global__ __launch_bounds__(256, 4) void gemm_fused_kernel(
    const int* __restrict__ rowbeg, const int* __restrict__ rowend,
    const int* __restrict__ col, const unsigned short* __restrict__ Xs,
    const unsigned short* __restrict__ W1s, const unsigned short* __restrict__ W2s,
    const float* __restrict__ bias, const float* __restrict__ dinv,
    unsigned short* __restrict__ T, int M) {
    __shared__ unsigned short lh[4][16 * LDSTRIDE];   // 4 waves x 8448 B
    int wave = threadIdx.x >> 6;
    int lane = threadIdx.x & 63;
    int mt = blockIdx.x * 4 + wave;
    int m0 = mt * 16;
    bool active = (m0 < M);
    int mrow = lane & 15, quad = lane >> 4;
    unsigned short* myl = lh[wave];

    if (active) {
        int rr = m0 + mrow; if (rr >= M) rr = M - 1;
        // ---- register-direct gather: acc[kc][j] over this row's in-edges ----
        float acc[4][8];
        const unsigned short* base = Xs + quad * 8;
#pragma unroll
        for (int kc = 0; kc < 4; kc++) {
            bf16x8 v = *(const bf16x8*)(base + (size_t)rr * 128 + kc * 32);
#pragma unroll
            for (int j = 0; j < 8; j++) acc[kc][j] = bf2f((unsigned short)v[j]);
        }
        int beg = rowbeg[rr], end = rowend[rr];
        int i = beg;
        for (; i + 3 < end; i += 4) {      // 4 edges x 4 chunks = 16 loads in flight
            size_t c0 = (size_t)col[i] * 128, c1 = (size_t)col[i + 1] * 128;
            size_t c2 = (size_t)col[i + 2] * 128, c3 = (size_t)col[i + 3] * 128;
            bf16x8 p0 = *(const bf16x8*)(base + c0);
            bf16x8 p1 = *(const bf16x8*)(base + c0 + 32);
            bf16x8 p2 = *(const bf16x8*)(base + c0 + 64);
            bf16x8 p3 = *(const bf16x8*)(base + c0 + 96);
            bf16x8 q0 = *(const bf16x8*)(base + c1);
            bf16x8 q1 = *(const bf16x8*)(base + c1 + 32);
            bf16x8 q2 = *(const bf16x8*)(base + c1 + 64);
            bf16x8 q3 = *(const bf16x8*)(base + c1 + 96);
            bf16x8 r0 = *(const bf16x8*)(base + c2);
            bf16x8 r1 = *(const bf16x8*)(base + c2 + 32);
            bf16x8 r2 = *(const bf16x8*)(base + c2 + 64);
            bf16x8 r3 = *(const bf16x8*)(base + c2 + 96);
            bf16x8 s0 = *(const bf16x8*)(base + c3);
            bf16x8 s1 = *(const bf16x8*)(base + c3 + 32);
            bf16x8 s2 = *(const bf16x8*)(base + c3 + 64);
            bf16x8 s3 = *(const bf16x8*)(base + c3 + 96);
#pragma unroll
            for (int j = 0; j < 8; j++) {
                acc[0][j] += (bf2f((unsigned short)p0[j]) + bf2f((unsigned short)q0[j]))
                           + (bf2f((unsigned short)r0[j]) + bf2f((unsigned short)s0[j]));
                acc[1][j] += (bf2f((unsigned short)p1[j]) + bf2f((unsigned short)q1[j]))
                           + (bf2f((unsigned short)r1[j]) + bf2f((unsigned short)s1[j]));
                acc[2][j] += (bf2f((unsigned short)p2[j]) + bf2f((unsigned short)q2[j]))
                           + (bf2f((unsigned short)r2[j]) + bf2f((unsigned short)s2[j]));
                acc[3][j] += (bf2f((unsigned short)p3[j]) + bf2f((unsigned short)q3[j]))
                           + (bf2f((unsigned short)r3[j]) + bf2f((unsigned short)s3[j]));
            }
        }
        for (; i + 1 < end; i += 2) {      // 2-edge tail
            size_t c0 = (size_t)col[i] * 128, c1 = (size_t)col[i + 1] * 128;
            bf16x8 p0 = *(const bf16x8*)(base + c0);
            bf16x8 p1 = *(const bf16x8*)(base + c0 + 32);
            bf16x8 p2 = *(const bf16x8*)(base + c0 + 64);
            bf16x8 p3 = *(const bf16x8*)(base + c0 + 96);
            bf16x8 q0 = *(const bf16x8*)(base + c1);
            bf16x8 q1 = *(const bf16x8*)(base + c1 + 32);
            bf16x8 q2 = *(const bf16x8*)(base + c1 + 64);
            bf16x8 q3 = *(const bf16x8*)(base + c1 + 96);
#pragma unroll
            for (int j = 0; j < 8; j++) {
                acc[0][j] += bf2f((unsigned short)p0[j]) + bf2f((unsigned short)q0[j]);
                acc[1][j] += bf2f((unsigned short)p1[j]) + bf2f((unsigned short)q1[j]);
                acc[2][j] += bf2f((unsigned short)p2[j]) + bf2f((unsigned short)q2[j]);
                acc[3][j] += bf2f((unsigned short)p3[j]) + bf2f((unsigned short)q3[j]);
            }
        }
        if (i < end) {
            size_t c0 = (size_t)col[i] * 128;
#pragma unroll
            for (int kc = 0; kc < 4; kc++) {
                bf16x8 p = *(const bf16x8*)(base + c0 + kc * 32);
#pragma unroll
                for (int j = 0; j < 8; j++) acc[kc][j] += bf2f((unsigned short)p[j]);
            }
        }
        float dvr = dinv[rr];
        bf16x8 a[4];
#pragma unroll
        for (int kc = 0; kc < 4; kc++)
#pragma unroll
            for (int j = 0; j < 8; j++)
                a[kc][j] = (short)f2bf(acc[kc][j] * dvr);

        // ---- GEMM1: H1 tile -> LDS (C-layout -> A-layout round trip) ----
        float dv[4];
#pragma unroll
        for (int i2 = 0; i2 < 4; i2++) {
            int gr = m0 + quad * 4 + i2;
            dv[i2] = dinv[gr < M ? gr : M - 1];
        }
        const bf16x8* w1v = (const bf16x8*)W1s;
        for (int nt = 0; nt < 16; nt++) {
            f32x4 c = {0.f, 0.f, 0.f, 0.f};
#pragma unroll
            for (int kc = 0; kc < 4; kc++) {
                bf16x8 b = w1v[(nt * 4 + kc) * 64 + lane];
                c = __builtin_amdgcn_mfma_f32_16x16x32_bf16(a[kc], b, c, 0, 0, 0);
            }
            int colc = nt * 16 + mrow;
            float bb = bias[colc];
#pragma unroll
            for (int i2 = 0; i2 < 4; i2++) {
                float v = fmaxf(c[i2] + bb, 0.f) * dv[i2];
                myl[(quad * 4 + i2) * LDSTRIDE + colc] = f2bf(v);
            }
        }
    }
    __syncthreads();
    if (active) {
        bf16x8 h[8];
        const unsigned short* hrow = myl + mrow * LDSTRIDE + quad * 8;
#pragma unroll
        for (int kc = 0; kc < 8; kc++) h[kc] = *(const bf16x8*)(hrow + kc * 32);
        const bf16x8* w2v = (const bf16x8*)W2s;
        for (int nt = 0; nt < 8; nt++) {
            f32x4 c = {0.f, 0.f, 0.f, 0.f};
#pragma unroll
            for (int kc = 0; kc < 8; kc++) {
                bf16x8 b = w2v[(nt * 8 + kc) * 64 + lane];
                c = __builtin_amdgcn_mfma_f32_16x16x32_bf16(h[kc], b, c, 0, 0, 0);
            }
            int colc = nt * 16 + mrow;
#pragma unroll
            for (int i2 = 0; i2 < 4; i2++) {
                int gr = m0 + quad * 4 + i2;
                if (gr < M) T[(size_t)gr * 128 + colc] = f2bf(c[i2]);
            }
        }
    }
}

extern "C" void kernel_launch(void* const* d_in, const int* in_sizes, int n_in,
                              void* d_out, int out_size, void* d_ws, size_t ws_size,
                              hipStream_t stream) {
    const float* x  = (const float*)d_in[0];
    const int* ei   = (const int*)d_in[1];     // int32 (JAX x64 disabled)
    const float* W1 = (const float*)d_in[2];
    const float* b1 = (const float*)d_in[3];
    const float* W2 = (const float*)d_in[4];
    const float* b2 = (const float*)d_in[5];
    float* out      = (float*)d_out;

    const int N = in_sizes[0] / 128;
    const int E = in_sizes[1] / 2;
    const int* src = ei;
    const int* dst = ei + E;

    const int nbuck = (N + BMASK) >> BSHIFT;                // 391
    const int cap = E / nbuck + E / (4 * nbuck) + 512;      // ~3069

    // Workspace: dinv | Ts | Xs | W1s | W2s | rowbeg | rowend | ctrl | bbuf | col
    float* ws = (float*)d_ws;
    size_t Np = ((size_t)N + 255) & ~(size_t)255;
    float*          dinv = ws;
    unsigned short* Ts   = (unsigned short*)(dinv + Np);    // N*128 bf16
    unsigned short* Xs   = Ts + (size_t)N * 128;            // N*128 bf16
    unsigned short* W1s  = Xs + (size_t)N * 128;            // 32768
    unsigned short* W2s  = W1s + 32768;                     // 32768
    int* rowbeg = (int*)(W2s + 32768);                      // N
    int* rowend = rowbeg + Np;                              // N
    int* ctrl   = rowend + Np;                              // bcur[512]
    int* bcur   = ctrl;
    unsigned int* bbuf = (unsigned int*)(ctrl + 512);       // nbuck*cap packed
    int* col    = (int*)(bbuf + (size_t)nbuck * cap);       // nbuck*cap

    // 1. weight swizzle + ctrl zero, then CSR build
    wswz_kernel<<<256, 256, 0, stream>>>(W1, W2, W1s, W2s, ctrl);
    int nbins = (E + 2047) / 2048;                          // 391
    bin_kernel<<<nbins, 256, 0, stream>>>(src, dst, bcur, bbuf, E, cap, nbuck);
    bucket_csr_kernel<<<nbuck, 256, 0, stream>>>(bcur, bbuf, x, col, rowbeg, rowend,
                                                 dinv, Xs, N, cap);

    // 2. fused gather1 + GEMM1 + GEMM2 -> Ts
    int mtiles = (N + 15) / 16;
    gemm_fused_kernel<<<(mtiles + 3) / 4, 256, 0, stream>>>(rowbeg, rowend, col, Xs,
                                                            W1s, W2s, b1, dinv, Ts, N);

    // 3. gather2 + fused bias/relu -> out
    int gth = N * 32;
    gather2_kernel<<<(gth + 255) / 256, 256, 0, stream>>>(rowbeg, rowend, col, Ts,
                                                          dinv, b2, out, N);
}